// Round 2
// baseline (624.800 us; speedup 1.0000x reference)
//
#include <hip/hip_runtime.h>
#include <hip/hip_cooperative_groups.h>
#include <math.h>

namespace cg = cooperative_groups;

#define N_NODES 4096
#define IN_DIM  1433
#define HID     64
#define OUT_DIM 7
#define FPAD    8       // padded feature stride for vectorized gathers
#define CAP     128     // max neighbors per node (avg 32, sigma 5.6; 128 >15 sigma)
#define BR      64      // rows per gemm1 block
#define KT      32      // k-tile

static constexpr float LAMBDA = (float)(1.0 / 0.9 - 1.0);   // 0.11111111
static constexpr float SCADA  = 3.7f;

// ---------------------------------------------------------------------------
// Kernel 1: extract sparse adjacency + degrees from dense binary A (zero diag)
// ---------------------------------------------------------------------------
__global__ __launch_bounds__(256) void build_adj(const float* __restrict__ A,
    int* __restrict__ nbr, int* __restrict__ cnt, float* __restrict__ deg,
    float* __restrict__ rsd) {
  int i = blockIdx.x;
  __shared__ int c;
  if (threadIdx.x == 0) c = 0;
  __syncthreads();
  const float4* row = (const float4*)(A + (size_t)i * N_NODES);
  for (int q = threadIdx.x; q < N_NODES / 4; q += 256) {
    float4 v = row[q];
    int j0 = q * 4;
    if (v.x != 0.0f) { int s = atomicAdd(&c, 1); if (s < CAP) nbr[(size_t)i * CAP + s] = j0; }
    if (v.y != 0.0f) { int s = atomicAdd(&c, 1); if (s < CAP) nbr[(size_t)i * CAP + s] = j0 + 1; }
    if (v.z != 0.0f) { int s = atomicAdd(&c, 1); if (s < CAP) nbr[(size_t)i * CAP + s] = j0 + 2; }
    if (v.w != 0.0f) { int s = atomicAdd(&c, 1); if (s < CAP) nbr[(size_t)i * CAP + s] = j0 + 3; }
  }
  __syncthreads();
  if (threadIdx.x == 0) {
    int cc = c; if (cc > CAP) cc = CAP;
    cnt[i] = cc;
    float d = (float)c + 1.0f;      // + self loop
    deg[i] = d;
    rsd[i] = 1.0f / sqrtf(d);
  }
}

// ---------------------------------------------------------------------------
// Kernel 2: P[ks] = X[:, kchunk] @ w1[kchunk, :]  (split-K partials, NO atomics)
// 64x64 tile, 256 threads, 4x4 register tile; grid (64, ksplit).
// ---------------------------------------------------------------------------
__global__ __launch_bounds__(256) void gemm1(const float* __restrict__ X,
    const float* __restrict__ w1, float* __restrict__ P, int ksplit) {
  __shared__ __align__(16) float Xs[KT][BR + 4];
  __shared__ __align__(16) float Ws[KT][HID];
  const int t  = threadIdx.x;
  const int r0 = blockIdx.x * BR;
  const int ks = blockIdx.y;
  const int kbeg = (IN_DIM * ks) / ksplit;
  const int kend = (IN_DIM * (ks + 1)) / ksplit;
  const int rg = t >> 4;
  const int cg = t & 15;

  float acc[4][4];
  #pragma unroll
  for (int r = 0; r < 4; ++r)
    #pragma unroll
    for (int c = 0; c < 4; ++c) acc[r][c] = 0.0f;

  for (int k0 = kbeg; k0 < kend; k0 += KT) {
    #pragma unroll
    for (int j = 0; j < (BR * KT) / 256; ++j) {
      int e = t + 256 * j;
      int row = e >> 5;
      int kk  = e & (KT - 1);
      int k   = k0 + kk;
      float v = (k < kend) ? X[(size_t)(r0 + row) * IN_DIM + k] : 0.0f;
      Xs[kk][row] = v;
    }
    #pragma unroll
    for (int j = 0; j < (HID * KT) / 256; ++j) {
      int e = t + 256 * j;
      int kk  = e >> 6;
      int col = e & 63;
      int k   = k0 + kk;
      Ws[kk][col] = (k < kend) ? w1[(size_t)k * HID + col] : 0.0f;
    }
    __syncthreads();
    #pragma unroll
    for (int kk = 0; kk < KT; ++kk) {
      const float4 xv = *(const float4*)&Xs[kk][rg * 4];
      const float4 wv = *(const float4*)&Ws[kk][cg * 4];
      float xr[4] = {xv.x, xv.y, xv.z, xv.w};
      float wc[4] = {wv.x, wv.y, wv.z, wv.w};
      #pragma unroll
      for (int r = 0; r < 4; ++r)
        #pragma unroll
        for (int c = 0; c < 4; ++c) acc[r][c] += xr[r] * wc[c];
    }
    __syncthreads();
  }
  float* Pp = P + (size_t)ks * N_NODES * HID;
  #pragma unroll
  for (int r = 0; r < 4; ++r) {
    int row = r0 + rg * 4 + r;
    float4 v = make_float4(acc[r][0], acc[r][1], acc[r][2], acc[r][3]);
    *(float4*)&Pp[(size_t)row * HID + cg * 4] = v;
  }
}

// ---------------------------------------------------------------------------
// Kernel 2b: H = sum over ksplit split-K partials (vectorized float4)
// ---------------------------------------------------------------------------
__global__ __launch_bounds__(256) void reduce_h(const float* __restrict__ P,
    float* __restrict__ H, int ksplit) {
  int idx4 = blockIdx.x * 256 + threadIdx.x;
  const float4* P4 = (const float4*)P;
  float4 s = P4[idx4];
  for (int ks = 1; ks < ksplit; ++ks) {
    float4 v = P4[(size_t)ks * (N_NODES * HID / 4) + idx4];
    s.x += v.x; s.y += v.y; s.z += v.z; s.w += v.w;
  }
  ((float4*)H)[idx4] = s;
}

// ---------------------------------------------------------------------------
// Kernel 3: F0 = relu(H + b1) @ w2 + b2 ; seed Fcur = F0. Padded stride 8.
// ---------------------------------------------------------------------------
__global__ __launch_bounds__(256) void mlp_out(const float* __restrict__ H,
    const float* __restrict__ b1, const float* __restrict__ w2,
    const float* __restrict__ b2, float* __restrict__ F0, float* __restrict__ Fcur) {
  int t = blockIdx.x * blockDim.x + threadIdx.x;
  if (t >= N_NODES * FPAD) return;
  int row = t >> 3, c = t & 7;
  if (c == 7) { F0[t] = 0.0f; Fcur[t] = 0.0f; return; }
  float acc = b2[c];
  const float* h = H + (size_t)row * HID;
  #pragma unroll
  for (int k = 0; k < HID; ++k) {
    float hv = fmaxf(h[k] + b1[k], 0.0f);
    acc += hv * w2[k * OUT_DIM + c];
  }
  F0[t] = acc;
  Fcur[t] = acc;
}

// ---------------------------------------------------------------------------
// Kernel 4 (fused): ALL 10 RUNG steps in one cooperative kernel.
// 32 lanes per node (avg degree 32 -> ~1 gather/lane), 512 blocks x 256 thr
// = 4096 node slots = 2 blocks/CU. grid.sync() between steps replaces 9
// dependent kernel launches. Neighbor ids + rsi*rsj cached in registers ONCE
// and reused across all 10 steps (manually unrolled x4: no runtime-indexed
// arrays -> no scratch).
// ---------------------------------------------------------------------------
__global__ __launch_bounds__(256) void rung_fused(const float* __restrict__ F0,
    float* __restrict__ FA, float* __restrict__ FB, float* __restrict__ out,
    const int* __restrict__ nbr, const int* __restrict__ cnt,
    const float* __restrict__ deg, const float* __restrict__ rsd,
    const float* __restrict__ lg0p, const float* __restrict__ rdp) {
  cg::grid_group grid = cg::this_grid();
  const int lane = threadIdx.x & 31;                       // lane within node group
  const int i = (blockIdx.x * 256 + threadIdx.x) >> 5;     // node id 0..4095

  const float r_ = 1.0f / (1.0f + expf(-rdp[0]));
  const float g0 = expf(lg0p[0]);
  const float rsi = rsd[i];
  const float Di  = deg[i];
  const int   ci  = cnt[i];

  // cache this lane's <=4 edges in registers for all 10 steps
  int   j0 = 0, j1 = 0, j2 = 0, j3 = 0;
  float q0 = 0.f, q1 = 0.f, q2 = 0.f, q3 = 0.f;   // rsj
  bool  e0 = (lane      < ci), e1 = (lane + 32 < ci),
        e2 = (lane + 64 < ci), e3 = (lane + 96 < ci);
  if (e0) { j0 = nbr[(size_t)i * CAP + lane     ]; q0 = rsd[j0]; }
  if (e1) { j1 = nbr[(size_t)i * CAP + lane + 32]; q1 = rsd[j1]; }
  if (e2) { j2 = nbr[(size_t)i * CAP + lane + 64]; q2 = rsd[j2]; }
  if (e3) { j3 = nbr[(size_t)i * CAP + lane + 96]; q3 = rsd[j3]; }

  const float* cur = FA;
  float*       nxt = FB;
  float rk = 1.0f;

  for (int k = 0; k < 10; ++k) {
    const float lam = g0 * rk * (1.0f / SCADA);
    rk *= r_;

    const float4* fpi = (const float4*)(cur + (size_t)i * FPAD);
    float4 a0 = fpi[0], a1 = fpi[1];
    float Fni[FPAD] = {a0.x * rsi, a0.y * rsi, a0.z * rsi, a0.w * rsi,
                       a1.x * rsi, a1.y * rsi, a1.z * rsi, a1.w * rsi};

    float s = 0.0f;
    float acc[FPAD] = {0, 0, 0, 0, 0, 0, 0, 0};

    #define EDGE(EN, JN, QN)                                                  \
    if (EN) {                                                                 \
      const float4* fp = (const float4*)(cur + (size_t)(JN) * FPAD);          \
      float4 b0 = fp[0], b1v = fp[1];                                         \
      float fj[FPAD] = {b0.x, b0.y, b0.z, b0.w, b1v.x, b1v.y, b1v.z, b1v.w};  \
      float d2 = 0.0f;                                                        \
      _Pragma("unroll")                                                       \
      for (int c = 0; c < FPAD; ++c) {                                        \
        float df = Fni[c] - fj[c] * (QN);                                     \
        d2 += df * df;                                                        \
      }                                                                       \
      float y = sqrtf(d2);                                                    \
      float w;                                                                \
      if (y <= lam)              w = 1.0f;                                    \
      else if (y <= SCADA * lam) w = (SCADA * lam - y) /                      \
                                     ((SCADA - 1.0f) * fmaxf(y, 1e-12f));     \
      else                       w = 0.0f;                                    \
      if (w != w) w = 1.0f;                                                   \
      s += w;                                                                 \
      float wr = w * rsi * (QN);                                              \
      _Pragma("unroll")                                                       \
      for (int c = 0; c < FPAD; ++c) acc[c] += wr * fj[c];                    \
    }
    EDGE(e0, j0, q0)
    EDGE(e1, j1, q1)
    EDGE(e2, j2, q2)
    EDGE(e3, j3, q3)
    #undef EDGE

    // reduce across the 32-lane node group (butterfly)
    #pragma unroll
    for (int off = 16; off > 0; off >>= 1) {
      s += __shfl_xor(s, off, 32);
      #pragma unroll
      for (int c = 0; c < FPAD; ++c) acc[c] += __shfl_xor(acc[c], off, 32);
    }

    if (k == 9) {
      if (lane == 0) {
        float inv = 1.0f / (s / Di + LAMBDA);
        #pragma unroll
        for (int c = 0; c < OUT_DIM; ++c)
          out[(size_t)i * OUT_DIM + c] =
              (acc[c] + LAMBDA * F0[(size_t)i * FPAD + c]) * inv;
      }
    } else {
      if (lane == 0) {
        float inv = 1.0f / (s / Di + LAMBDA);
        float o[FPAD];
        #pragma unroll
        for (int c = 0; c < FPAD; ++c)
          o[c] = (acc[c] + LAMBDA * F0[(size_t)i * FPAD + c]) * inv;  // pad stays 0
        float4* op = (float4*)(nxt + (size_t)i * FPAD);
        op[0] = make_float4(o[0], o[1], o[2], o[3]);
        op[1] = make_float4(o[4], o[5], o[6], o[7]);
      }
      grid.sync();               // uniform across grid: k<9 for everyone
      const float* tmp = cur; cur = nxt; nxt = (float*)tmp;
    }
  }
}

// ---------------------------------------------------------------------------
extern "C" void kernel_launch(void* const* d_in, const int* in_sizes, int n_in,
                              void* d_out, int out_size, void* d_ws, size_t ws_size,
                              hipStream_t stream) {
  const float* A   = (const float*)d_in[0];
  const float* X   = (const float*)d_in[1];
  const float* w1  = (const float*)d_in[2];
  const float* b1  = (const float*)d_in[3];
  const float* w2  = (const float*)d_in[4];
  const float* b2  = (const float*)d_in[5];
  const float* lg0 = (const float*)d_in[6];
  const float* rd  = (const float*)d_in[7];
  float* out = (float*)d_out;

  const size_t fixed = (size_t)N_NODES * CAP * sizeof(int)
                     + (size_t)N_NODES * sizeof(int)
                     + (size_t)N_NODES * sizeof(float) * 2
                     + (size_t)N_NODES * HID * sizeof(float)
                     + (size_t)N_NODES * FPAD * sizeof(float) * 3;
  const size_t pbuf = (size_t)N_NODES * HID * sizeof(float);
  int ksplit = (ws_size >= fixed + 16 * pbuf) ? 16 : 8;

  char* w = (char*)d_ws;
  int*   nbr = (int*)w;   w += (size_t)N_NODES * CAP * sizeof(int);
  int*   cnt = (int*)w;   w += (size_t)N_NODES * sizeof(int);
  float* deg = (float*)w; w += (size_t)N_NODES * sizeof(float);
  float* rsd = (float*)w; w += (size_t)N_NODES * sizeof(float);
  float* P   = (float*)w; w += (size_t)ksplit * N_NODES * HID * sizeof(float);
  float* H   = (float*)w; w += (size_t)N_NODES * HID * sizeof(float);
  float* F0  = (float*)w; w += (size_t)N_NODES * FPAD * sizeof(float);
  float* FA  = (float*)w; w += (size_t)N_NODES * FPAD * sizeof(float);
  float* FB  = (float*)w; w += (size_t)N_NODES * FPAD * sizeof(float);

  build_adj<<<N_NODES, 256, 0, stream>>>(A, nbr, cnt, deg, rsd);
  gemm1<<<dim3(N_NODES / BR, ksplit), 256, 0, stream>>>(X, w1, P, ksplit);
  reduce_h<<<(N_NODES * HID / 4) / 256, 256, 0, stream>>>(P, H, ksplit);
  mlp_out<<<(N_NODES * FPAD) / 256, 256, 0, stream>>>(H, b1, w2, b2, F0, FA);

  void* args[] = {(void*)&F0, (void*)&FA, (void*)&FB, (void*)&out,
                  (void*)&nbr, (void*)&cnt, (void*)&deg, (void*)&rsd,
                  (void*)&lg0, (void*)&rd};
  hipLaunchCooperativeKernel((void*)rung_fused, dim3(N_NODES / 8), dim3(256),
                             args, 0, stream);
}

// Round 3
// 320.168 us; speedup vs baseline: 1.9515x; 1.9515x over previous
//
#include <hip/hip_runtime.h>
#include <math.h>

#define N_NODES 4096
#define IN_DIM  1433
#define HID     64
#define OUT_DIM 7
#define FPAD    8       // padded feature stride for vectorized gathers
#define CAP     128     // max neighbors per node (avg 32, sigma 5.6; 128 >15 sigma)
#define BR      64      // rows per gemm1 block
#define KT      32      // k-tile
#define NBLK    64      // blocks in fused propagation kernel (<< 256 CUs: co-resident)

static constexpr float LAMBDA = (float)(1.0 / 0.9 - 1.0);   // 0.11111111
static constexpr float SCADA  = 3.7f;

// ---------------------------------------------------------------------------
// Kernel 1: extract sparse adjacency + degrees from dense binary A (zero diag)
// Also zero-inits the global barrier state (stream-ordered before rung_fused;
// re-done every launch since the harness poisons the workspace between reps).
// ---------------------------------------------------------------------------
__global__ __launch_bounds__(256) void build_adj(const float* __restrict__ A,
    int* __restrict__ nbr, int* __restrict__ cnt, float* __restrict__ deg,
    float* __restrict__ rsd, unsigned* __restrict__ bar) {
  int i = blockIdx.x;
  if (i == 0 && threadIdx.x < 2) bar[threadIdx.x] = 0u;   // {arrive_cnt, epoch}
  __shared__ int c;
  if (threadIdx.x == 0) c = 0;
  __syncthreads();
  const float4* row = (const float4*)(A + (size_t)i * N_NODES);
  for (int q = threadIdx.x; q < N_NODES / 4; q += 256) {
    float4 v = row[q];
    int j0 = q * 4;
    if (v.x != 0.0f) { int s = atomicAdd(&c, 1); if (s < CAP) nbr[(size_t)i * CAP + s] = j0; }
    if (v.y != 0.0f) { int s = atomicAdd(&c, 1); if (s < CAP) nbr[(size_t)i * CAP + s] = j0 + 1; }
    if (v.z != 0.0f) { int s = atomicAdd(&c, 1); if (s < CAP) nbr[(size_t)i * CAP + s] = j0 + 2; }
    if (v.w != 0.0f) { int s = atomicAdd(&c, 1); if (s < CAP) nbr[(size_t)i * CAP + s] = j0 + 3; }
  }
  __syncthreads();
  if (threadIdx.x == 0) {
    int cc = c; if (cc > CAP) cc = CAP;
    cnt[i] = cc;
    float d = (float)c + 1.0f;      // + self loop
    deg[i] = d;
    rsd[i] = 1.0f / sqrtf(d);
  }
}

// ---------------------------------------------------------------------------
// Kernel 2: P[ks] = X[:, kchunk] @ w1[kchunk, :]  (split-K partials, NO atomics)
// 64x64 tile, 256 threads, 4x4 register tile; grid (64, ksplit).
// ---------------------------------------------------------------------------
__global__ __launch_bounds__(256) void gemm1(const float* __restrict__ X,
    const float* __restrict__ w1, float* __restrict__ P, int ksplit) {
  __shared__ __align__(16) float Xs[KT][BR + 4];
  __shared__ __align__(16) float Ws[KT][HID];
  const int t  = threadIdx.x;
  const int r0 = blockIdx.x * BR;
  const int ks = blockIdx.y;
  const int kbeg = (IN_DIM * ks) / ksplit;
  const int kend = (IN_DIM * (ks + 1)) / ksplit;
  const int rg = t >> 4;
  const int cg = t & 15;

  float acc[4][4];
  #pragma unroll
  for (int r = 0; r < 4; ++r)
    #pragma unroll
    for (int c = 0; c < 4; ++c) acc[r][c] = 0.0f;

  for (int k0 = kbeg; k0 < kend; k0 += KT) {
    #pragma unroll
    for (int j = 0; j < (BR * KT) / 256; ++j) {
      int e = t + 256 * j;
      int row = e >> 5;
      int kk  = e & (KT - 1);
      int k   = k0 + kk;
      float v = (k < kend) ? X[(size_t)(r0 + row) * IN_DIM + k] : 0.0f;
      Xs[kk][row] = v;
    }
    #pragma unroll
    for (int j = 0; j < (HID * KT) / 256; ++j) {
      int e = t + 256 * j;
      int kk  = e >> 6;
      int col = e & 63;
      int k   = k0 + kk;
      Ws[kk][col] = (k < kend) ? w1[(size_t)k * HID + col] : 0.0f;
    }
    __syncthreads();
    #pragma unroll
    for (int kk = 0; kk < KT; ++kk) {
      const float4 xv = *(const float4*)&Xs[kk][rg * 4];
      const float4 wv = *(const float4*)&Ws[kk][cg * 4];
      float xr[4] = {xv.x, xv.y, xv.z, xv.w};
      float wc[4] = {wv.x, wv.y, wv.z, wv.w};
      #pragma unroll
      for (int r = 0; r < 4; ++r)
        #pragma unroll
        for (int c = 0; c < 4; ++c) acc[r][c] += xr[r] * wc[c];
    }
    __syncthreads();
  }
  float* Pp = P + (size_t)ks * N_NODES * HID;
  #pragma unroll
  for (int r = 0; r < 4; ++r) {
    int row = r0 + rg * 4 + r;
    float4 v = make_float4(acc[r][0], acc[r][1], acc[r][2], acc[r][3]);
    *(float4*)&Pp[(size_t)row * HID + cg * 4] = v;
  }
}

// ---------------------------------------------------------------------------
// Kernel 2b: H = sum over ksplit split-K partials (vectorized float4)
// ---------------------------------------------------------------------------
__global__ __launch_bounds__(256) void reduce_h(const float* __restrict__ P,
    float* __restrict__ H, int ksplit) {
  int idx4 = blockIdx.x * 256 + threadIdx.x;
  const float4* P4 = (const float4*)P;
  float4 s = P4[idx4];
  for (int ks = 1; ks < ksplit; ++ks) {
    float4 v = P4[(size_t)ks * (N_NODES * HID / 4) + idx4];
    s.x += v.x; s.y += v.y; s.z += v.z; s.w += v.w;
  }
  ((float4*)H)[idx4] = s;
}

// ---------------------------------------------------------------------------
// Kernel 3: F0 = relu(H + b1) @ w2 + b2 ; seed Fcur = F0. Padded stride 8.
// ---------------------------------------------------------------------------
__global__ __launch_bounds__(256) void mlp_out(const float* __restrict__ H,
    const float* __restrict__ b1, const float* __restrict__ w2,
    const float* __restrict__ b2, float* __restrict__ F0, float* __restrict__ Fcur) {
  int t = blockIdx.x * blockDim.x + threadIdx.x;
  if (t >= N_NODES * FPAD) return;
  int row = t >> 3, c = t & 7;
  if (c == 7) { F0[t] = 0.0f; Fcur[t] = 0.0f; return; }
  float acc = b2[c];
  const float* h = H + (size_t)row * HID;
  #pragma unroll
  for (int k = 0; k < HID; ++k) {
    float hv = fmaxf(h[k] + b1[k], 0.0f);
    acc += hv * w2[k * OUT_DIM + c];
  }
  F0[t] = acc;
  Fcur[t] = acc;
}

// ---------------------------------------------------------------------------
// Hand-rolled inter-workgroup barrier (agent scope, monotonic epoch).
// Leader-only arrival/poll; NBLK=64 participants (all co-resident).
// Release: __syncthreads drains vmcnt -> leader __threadfence (L2 writeback)
// -> atomicAdd arrival. Epoch bump happens only after ALL blocks' writebacks.
// Acquire: epoch load (acquire) -> __threadfence (invalidate) -> __syncthreads.
// ---------------------------------------------------------------------------
__device__ __forceinline__ void grid_barrier(unsigned* __restrict__ bar,
                                             unsigned target) {
  __syncthreads();
  if (threadIdx.x == 0) {
    __threadfence();
    unsigned arr = __hip_atomic_fetch_add(&bar[0], 1u, __ATOMIC_ACQ_REL,
                                          __HIP_MEMORY_SCOPE_AGENT);
    if (arr == (unsigned)NBLK - 1u) {
      __hip_atomic_store(&bar[0], 0u, __ATOMIC_RELAXED, __HIP_MEMORY_SCOPE_AGENT);
      __hip_atomic_fetch_add(&bar[1], 1u, __ATOMIC_ACQ_REL,
                             __HIP_MEMORY_SCOPE_AGENT);
    } else {
      while (__hip_atomic_load(&bar[1], __ATOMIC_ACQUIRE,
                               __HIP_MEMORY_SCOPE_AGENT) < target) {
        __builtin_amdgcn_s_sleep(2);
      }
    }
    __threadfence();
  }
  __syncthreads();
}

// ---------------------------------------------------------------------------
// Kernel 4 (fused): ALL 10 RUNG steps, one launch, custom barrier.
// 64 blocks x 256 threads = 16384 threads = 4 lanes/node.
// Each lane caches its first 8 edges (j, rsj) in NAMED registers once
// (covers ci<=32, i.e. edge index lane+4t, t<8); tail loop covers ci>32.
// ---------------------------------------------------------------------------
__global__ __launch_bounds__(256) void rung_fused(const float* __restrict__ F0,
    float* __restrict__ FA, float* __restrict__ FB, float* __restrict__ out,
    const int* __restrict__ nbr, const int* __restrict__ cnt,
    const float* __restrict__ deg, const float* __restrict__ rsd,
    const float* __restrict__ lg0p, const float* __restrict__ rdp,
    unsigned* __restrict__ bar) {
  const int lane = threadIdx.x & 3;                        // lane within node group
  const int i = (blockIdx.x * 256 + threadIdx.x) >> 2;     // node id 0..4095

  const float r_ = 1.0f / (1.0f + expf(-rdp[0]));
  const float g0 = expf(lg0p[0]);
  const float rsi = rsd[i];
  const float Di  = deg[i];
  const int   ci  = cnt[i];

  // cache first 8 edges of this lane (edge indices lane+4t) in registers
  const int* nb = nbr + (size_t)i * CAP;
  int   j0=0,j1=0,j2=0,j3=0,j4=0,j5=0,j6=0,j7=0;
  float q0=0,q1=0,q2=0,q3=0,q4=0,q5=0,q6=0,q7=0;
  bool  e0=(lane    <ci), e1=(lane+ 4<ci), e2=(lane+ 8<ci), e3=(lane+12<ci),
        e4=(lane+16<ci), e5=(lane+20<ci), e6=(lane+24<ci), e7=(lane+28<ci);
  if (e0) { j0 = nb[lane     ]; q0 = rsd[j0]; }
  if (e1) { j1 = nb[lane +  4]; q1 = rsd[j1]; }
  if (e2) { j2 = nb[lane +  8]; q2 = rsd[j2]; }
  if (e3) { j3 = nb[lane + 12]; q3 = rsd[j3]; }
  if (e4) { j4 = nb[lane + 16]; q4 = rsd[j4]; }
  if (e5) { j5 = nb[lane + 20]; q5 = rsd[j5]; }
  if (e6) { j6 = nb[lane + 24]; q6 = rsd[j6]; }
  if (e7) { j7 = nb[lane + 28]; q7 = rsd[j7]; }

  const float* cur = FA;
  float*       nxt = FB;
  float rk = 1.0f;

  for (int k = 0; k < 10; ++k) {
    const float lam = g0 * rk * (1.0f / SCADA);
    rk *= r_;

    const float4* fpi = (const float4*)(cur + (size_t)i * FPAD);
    float4 a0 = fpi[0], a1 = fpi[1];
    float Fni[FPAD] = {a0.x * rsi, a0.y * rsi, a0.z * rsi, a0.w * rsi,
                       a1.x * rsi, a1.y * rsi, a1.z * rsi, a1.w * rsi};

    float s = 0.0f;
    float acc[FPAD] = {0, 0, 0, 0, 0, 0, 0, 0};

    #define EDGE(EN, JN, QN)                                                  \
    if (EN) {                                                                 \
      const float4* fp = (const float4*)(cur + (size_t)(JN) * FPAD);          \
      float4 b0 = fp[0], b1v = fp[1];                                         \
      float fj[FPAD] = {b0.x, b0.y, b0.z, b0.w, b1v.x, b1v.y, b1v.z, b1v.w};  \
      float d2 = 0.0f;                                                        \
      _Pragma("unroll")                                                       \
      for (int c = 0; c < FPAD; ++c) {                                        \
        float df = Fni[c] - fj[c] * (QN);                                     \
        d2 += df * df;                                                        \
      }                                                                       \
      float y = sqrtf(d2);                                                    \
      float w;                                                                \
      if (y <= lam)              w = 1.0f;                                    \
      else if (y <= SCADA * lam) w = (SCADA * lam - y) /                      \
                                     ((SCADA - 1.0f) * fmaxf(y, 1e-12f));     \
      else                       w = 0.0f;                                    \
      if (w != w) w = 1.0f;                                                   \
      s += w;                                                                 \
      float wr = w * rsi * (QN);                                              \
      _Pragma("unroll")                                                       \
      for (int c = 0; c < FPAD; ++c) acc[c] += wr * fj[c];                    \
    }
    EDGE(e0, j0, q0) EDGE(e1, j1, q1) EDGE(e2, j2, q2) EDGE(e3, j3, q3)
    EDGE(e4, j4, q4) EDGE(e5, j5, q5) EDGE(e6, j6, q6) EDGE(e7, j7, q7)

    // tail: edges with index >= 32 (ci > 32), read nbr directly
    for (int l = lane + 32; l < ci; l += 4) {
      int jt = nb[l];
      float qt = rsd[jt];
      EDGE(true, jt, qt)
    }
    #undef EDGE

    // reduce across the 4-lane node group
    #pragma unroll
    for (int off = 2; off > 0; off >>= 1) {
      s += __shfl_xor(s, off, 4);
      #pragma unroll
      for (int c = 0; c < FPAD; ++c) acc[c] += __shfl_xor(acc[c], off, 4);
    }

    if (k == 9) {
      if (lane == 0) {
        float inv = 1.0f / (s / Di + LAMBDA);
        #pragma unroll
        for (int c = 0; c < OUT_DIM; ++c)
          out[(size_t)i * OUT_DIM + c] =
              (acc[c] + LAMBDA * F0[(size_t)i * FPAD + c]) * inv;
      }
    } else {
      if (lane == 0) {
        float inv = 1.0f / (s / Di + LAMBDA);
        float o[FPAD];
        #pragma unroll
        for (int c = 0; c < FPAD; ++c)
          o[c] = (acc[c] + LAMBDA * F0[(size_t)i * FPAD + c]) * inv;  // pad stays 0
        float4* op = (float4*)(nxt + (size_t)i * FPAD);
        op[0] = make_float4(o[0], o[1], o[2], o[3]);
        op[1] = make_float4(o[4], o[5], o[6], o[7]);
      }
      grid_barrier(bar, (unsigned)(k + 1));
      const float* tmp = cur; cur = nxt; nxt = (float*)tmp;
    }
  }
}

// ---------------------------------------------------------------------------
extern "C" void kernel_launch(void* const* d_in, const int* in_sizes, int n_in,
                              void* d_out, int out_size, void* d_ws, size_t ws_size,
                              hipStream_t stream) {
  const float* A   = (const float*)d_in[0];
  const float* X   = (const float*)d_in[1];
  const float* w1  = (const float*)d_in[2];
  const float* b1  = (const float*)d_in[3];
  const float* w2  = (const float*)d_in[4];
  const float* b2  = (const float*)d_in[5];
  const float* lg0 = (const float*)d_in[6];
  const float* rd  = (const float*)d_in[7];
  float* out = (float*)d_out;

  const size_t fixed = (size_t)N_NODES * CAP * sizeof(int)
                     + (size_t)N_NODES * sizeof(int)
                     + (size_t)N_NODES * sizeof(float) * 2
                     + (size_t)N_NODES * HID * sizeof(float)
                     + (size_t)N_NODES * FPAD * sizeof(float) * 3
                     + 256;                                  // barrier state
  const size_t pbuf = (size_t)N_NODES * HID * sizeof(float);
  int ksplit = (ws_size >= fixed + 16 * pbuf) ? 16 : 8;

  char* w = (char*)d_ws;
  int*   nbr = (int*)w;   w += (size_t)N_NODES * CAP * sizeof(int);
  int*   cnt = (int*)w;   w += (size_t)N_NODES * sizeof(int);
  float* deg = (float*)w; w += (size_t)N_NODES * sizeof(float);
  float* rsd = (float*)w; w += (size_t)N_NODES * sizeof(float);
  float* P   = (float*)w; w += (size_t)ksplit * N_NODES * HID * sizeof(float);
  float* H   = (float*)w; w += (size_t)N_NODES * HID * sizeof(float);
  float* F0  = (float*)w; w += (size_t)N_NODES * FPAD * sizeof(float);
  float* FA  = (float*)w; w += (size_t)N_NODES * FPAD * sizeof(float);
  float* FB  = (float*)w; w += (size_t)N_NODES * FPAD * sizeof(float);
  unsigned* bar = (unsigned*)w;  // {arrive_cnt, epoch}

  build_adj<<<N_NODES, 256, 0, stream>>>(A, nbr, cnt, deg, rsd, bar);
  gemm1<<<dim3(N_NODES / BR, ksplit), 256, 0, stream>>>(X, w1, P, ksplit);
  reduce_h<<<(N_NODES * HID / 4) / 256, 256, 0, stream>>>(P, H, ksplit);
  mlp_out<<<(N_NODES * FPAD) / 256, 256, 0, stream>>>(H, b1, w2, b2, F0, FA);

  rung_fused<<<NBLK, 256, 0, stream>>>(F0, FA, FB, out, nbr, cnt, deg, rsd,
                                       lg0, rd, bar);
}

// Round 5
// 209.588 us; speedup vs baseline: 2.9811x; 1.5276x over previous
//
#include <hip/hip_runtime.h>
#include <math.h>

#define N_NODES 4096
#define IN_DIM  1433
#define HID     64
#define OUT_DIM 7
#define FPAD    8       // padded feature stride for vectorized gathers
#define CAP     128     // max neighbors per node (avg 32, sigma 5.6; 128 >15 sigma)
#define BR      64      // rows per gemm1 block
#define KT      32      // k-tile
#define LPN     16      // lanes per node in rung_step (avg degree 32 -> 2 edges/lane)

static constexpr float LAMBDA = (float)(1.0 / 0.9 - 1.0);   // 0.11111111
static constexpr float SCADA  = 3.7f;

// ---------------------------------------------------------------------------
// Kernel 1: extract sparse adjacency + degrees from dense binary A (zero diag)
// Thread (0,0) also precomputes the 10-entry lam_k table (saves per-thread
// expf/sigmoid/pow in every rung_step launch).
// ---------------------------------------------------------------------------
__global__ __launch_bounds__(256) void build_adj(const float* __restrict__ A,
    int* __restrict__ nbr, int* __restrict__ cnt, float* __restrict__ deg,
    float* __restrict__ rsd, float* __restrict__ lamt,
    const float* __restrict__ lg0p, const float* __restrict__ rdp) {
  int i = blockIdx.x;
  if (i == 0 && threadIdx.x == 0) {
    float r_ = 1.0f / (1.0f + expf(-rdp[0]));
    float g  = expf(lg0p[0]) * (1.0f / SCADA);
    #pragma unroll
    for (int k = 0; k < 10; ++k) { lamt[k] = g; g *= r_; }
  }
  __shared__ int c;
  if (threadIdx.x == 0) c = 0;
  __syncthreads();
  const float4* row = (const float4*)(A + (size_t)i * N_NODES);
  for (int q = threadIdx.x; q < N_NODES / 4; q += 256) {
    float4 v = row[q];
    int j0 = q * 4;
    if (v.x != 0.0f) { int s = atomicAdd(&c, 1); if (s < CAP) nbr[(size_t)i * CAP + s] = j0; }
    if (v.y != 0.0f) { int s = atomicAdd(&c, 1); if (s < CAP) nbr[(size_t)i * CAP + s] = j0 + 1; }
    if (v.z != 0.0f) { int s = atomicAdd(&c, 1); if (s < CAP) nbr[(size_t)i * CAP + s] = j0 + 2; }
    if (v.w != 0.0f) { int s = atomicAdd(&c, 1); if (s < CAP) nbr[(size_t)i * CAP + s] = j0 + 3; }
  }
  __syncthreads();
  if (threadIdx.x == 0) {
    int cc = c; if (cc > CAP) cc = CAP;
    cnt[i] = cc;
    float d = (float)c + 1.0f;      // + self loop
    deg[i] = d;
    rsd[i] = 1.0f / sqrtf(d);
  }
}

// ---------------------------------------------------------------------------
// Kernel 1b: pack per-edge {j, rsd[j]} so rung_step's per-edge chain is
// one 8B load + one 32B load (removes the dependent rsd[j] gather from
// every edge of every one of the 10 steps).
// ---------------------------------------------------------------------------
__global__ __launch_bounds__(128) void pack_edges(const int* __restrict__ nbr,
    const int* __restrict__ cnt, const float* __restrict__ rsd,
    int2* __restrict__ ej) {
  int i = blockIdx.x;
  int s = threadIdx.x;               // CAP = 128
  if (s < cnt[i]) {
    int j = nbr[(size_t)i * CAP + s];
    ej[(size_t)i * CAP + s] = make_int2(j, __float_as_int(rsd[j]));
  }
}

// ---------------------------------------------------------------------------
// Kernel 2: P[ks] = X[:, kchunk] @ w1[kchunk, :]  (split-K partials)
// 64x64 tile, 256 threads, 4x4 register tile; grid (64, ksplit).
// ---------------------------------------------------------------------------
__global__ __launch_bounds__(256) void gemm1(const float* __restrict__ X,
    const float* __restrict__ w1, float* __restrict__ P, int ksplit) {
  __shared__ __align__(16) float Xs[KT][BR + 4];
  __shared__ __align__(16) float Ws[KT][HID];
  const int t  = threadIdx.x;
  const int r0 = blockIdx.x * BR;
  const int ks = blockIdx.y;
  const int kbeg = (IN_DIM * ks) / ksplit;
  const int kend = (IN_DIM * (ks + 1)) / ksplit;
  const int rg = t >> 4;
  const int cg = t & 15;

  float acc[4][4];
  #pragma unroll
  for (int r = 0; r < 4; ++r)
    #pragma unroll
    for (int c = 0; c < 4; ++c) acc[r][c] = 0.0f;

  for (int k0 = kbeg; k0 < kend; k0 += KT) {
    #pragma unroll
    for (int j = 0; j < (BR * KT) / 256; ++j) {
      int e = t + 256 * j;
      int row = e >> 5;
      int kk  = e & (KT - 1);
      int k   = k0 + kk;
      float v = (k < kend) ? X[(size_t)(r0 + row) * IN_DIM + k] : 0.0f;
      Xs[kk][row] = v;
    }
    #pragma unroll
    for (int j = 0; j < (HID * KT) / 256; ++j) {
      int e = t + 256 * j;
      int kk  = e >> 6;
      int col = e & 63;
      int k   = k0 + kk;
      Ws[kk][col] = (k < kend) ? w1[(size_t)k * HID + col] : 0.0f;
    }
    __syncthreads();
    #pragma unroll
    for (int kk = 0; kk < KT; ++kk) {
      const float4 xv = *(const float4*)&Xs[kk][rg * 4];
      const float4 wv = *(const float4*)&Ws[kk][cg * 4];
      float xr[4] = {xv.x, xv.y, xv.z, xv.w};
      float wc[4] = {wv.x, wv.y, wv.z, wv.w};
      #pragma unroll
      for (int r = 0; r < 4; ++r)
        #pragma unroll
        for (int c = 0; c < 4; ++c) acc[r][c] += xr[r] * wc[c];
    }
    __syncthreads();
  }
  float* Pp = P + (size_t)ks * N_NODES * HID;
  #pragma unroll
  for (int r = 0; r < 4; ++r) {
    int row = r0 + rg * 4 + r;
    float4 v = make_float4(acc[r][0], acc[r][1], acc[r][2], acc[r][3]);
    *(float4*)&Pp[(size_t)row * HID + cg * 4] = v;
  }
}

// ---------------------------------------------------------------------------
// Kernel 2b: H = sum over ksplit split-K partials (vectorized float4)
// ---------------------------------------------------------------------------
__global__ __launch_bounds__(256) void reduce_h(const float* __restrict__ P,
    float* __restrict__ H, int ksplit) {
  int idx4 = blockIdx.x * 256 + threadIdx.x;
  const float4* P4 = (const float4*)P;
  float4 s = P4[idx4];
  for (int ks = 1; ks < ksplit; ++ks) {
    float4 v = P4[(size_t)ks * (N_NODES * HID / 4) + idx4];
    s.x += v.x; s.y += v.y; s.z += v.z; s.w += v.w;
  }
  ((float4*)H)[idx4] = s;
}

// ---------------------------------------------------------------------------
// Kernel 3: F0 = relu(H + b1) @ w2 + b2 ; seed Fcur = F0. Padded stride 8.
// ---------------------------------------------------------------------------
__global__ __launch_bounds__(256) void mlp_out(const float* __restrict__ H,
    const float* __restrict__ b1, const float* __restrict__ w2,
    const float* __restrict__ b2, float* __restrict__ F0, float* __restrict__ Fcur) {
  int t = blockIdx.x * blockDim.x + threadIdx.x;
  if (t >= N_NODES * FPAD) return;
  int row = t >> 3, c = t & 7;
  if (c == 7) { F0[t] = 0.0f; Fcur[t] = 0.0f; return; }
  float acc = b2[c];
  const float* h = H + (size_t)row * HID;
  #pragma unroll
  for (int k = 0; k < HID; ++k) {
    float hv = fmaxf(h[k] + b1[k], 0.0f);
    acc += hv * w2[k * OUT_DIM + c];
  }
  F0[t] = acc;
  Fcur[t] = acc;
}

// ---------------------------------------------------------------------------
// Kernel 4: one RUNG propagation step. 16 lanes per node (avg degree 32 ->
// ~2 edges/lane, 2 independent gather chains), 4-level shuffle reduce.
// Grid 256 blocks x 256 threads.
// ---------------------------------------------------------------------------
__global__ __launch_bounds__(256) void rung_step(const float* __restrict__ Fin,
    const float* __restrict__ F0, float* __restrict__ Fout,
    const int2* __restrict__ ej, const int* __restrict__ cnt,
    const float* __restrict__ deg, const float* __restrict__ rsd,
    const float* __restrict__ lamt, int kstep, int last) {
  const int lane = threadIdx.x & (LPN - 1);
  const int i = (blockIdx.x * 256 + threadIdx.x) / LPN;    // node id 0..4095

  const float lam = lamt[kstep];
  const float rsi = rsd[i];
  const float Di  = deg[i];
  const int   ci  = cnt[i];

  float Fni[FPAD];
  {
    const float4* fp = (const float4*)(Fin + (size_t)i * FPAD);
    float4 a0 = fp[0], a1 = fp[1];
    Fni[0] = a0.x * rsi; Fni[1] = a0.y * rsi; Fni[2] = a0.z * rsi; Fni[3] = a0.w * rsi;
    Fni[4] = a1.x * rsi; Fni[5] = a1.y * rsi; Fni[6] = a1.z * rsi; Fni[7] = a1.w * rsi;
  }
  float s = 0.0f;
  float acc[FPAD] = {0, 0, 0, 0, 0, 0, 0, 0};
  const int2* ep = ej + (size_t)i * CAP;
  for (int l = lane; l < ci; l += LPN) {
    int2 e = ep[l];
    int   j   = e.x;
    float rsj = __int_as_float(e.y);
    const float4* fp = (const float4*)(Fin + (size_t)j * FPAD);
    float4 b0 = fp[0], b1v = fp[1];
    float fj[FPAD] = {b0.x, b0.y, b0.z, b0.w, b1v.x, b1v.y, b1v.z, b1v.w};
    float d2 = 0.0f;
    #pragma unroll
    for (int c = 0; c < FPAD; ++c) {
      float df = Fni[c] - fj[c] * rsj;
      d2 += df * df;
    }
    float y = sqrtf(d2);
    float w;
    if (y <= lam)              w = 1.0f;
    else if (y <= SCADA * lam) w = (SCADA * lam - y) / ((SCADA - 1.0f) * fmaxf(y, 1e-12f));
    else                       w = 0.0f;
    if (w != w) w = 1.0f;      // NaN guard (matches reference)
    s += w;
    float wr = w * rsi * rsj;  // W_ij * A_tilde_ij
    #pragma unroll
    for (int c = 0; c < FPAD; ++c) acc[c] += wr * fj[c];
  }
  // reduce across the 16-lane node group (butterfly, 4 levels)
  #pragma unroll
  for (int off = LPN / 2; off > 0; off >>= 1) {
    s += __shfl_xor(s, off, LPN);
    #pragma unroll
    for (int c = 0; c < FPAD; ++c) acc[c] += __shfl_xor(acc[c], off, LPN);
  }
  if (lane == 0) {
    float Q = s / Di + LAMBDA;
    float inv = 1.0f / Q;
    if (last) {
      #pragma unroll
      for (int c = 0; c < OUT_DIM; ++c)
        Fout[(size_t)i * OUT_DIM + c] = (acc[c] + LAMBDA * F0[(size_t)i * FPAD + c]) * inv;
    } else {
      float o[FPAD];
      #pragma unroll
      for (int c = 0; c < FPAD; ++c)
        o[c] = (acc[c] + LAMBDA * F0[(size_t)i * FPAD + c]) * inv;   // pad col stays 0
      float4* op = (float4*)(Fout + (size_t)i * FPAD);
      op[0] = make_float4(o[0], o[1], o[2], o[3]);
      op[1] = make_float4(o[4], o[5], o[6], o[7]);
    }
  }
}

// ---------------------------------------------------------------------------
extern "C" void kernel_launch(void* const* d_in, const int* in_sizes, int n_in,
                              void* d_out, int out_size, void* d_ws, size_t ws_size,
                              hipStream_t stream) {
  const float* A   = (const float*)d_in[0];
  const float* X   = (const float*)d_in[1];
  const float* w1  = (const float*)d_in[2];
  const float* b1  = (const float*)d_in[3];
  const float* w2  = (const float*)d_in[4];
  const float* b2  = (const float*)d_in[5];
  const float* lg0 = (const float*)d_in[6];
  const float* rd  = (const float*)d_in[7];
  float* out = (float*)d_out;

  const size_t fixed = (size_t)N_NODES * CAP * sizeof(int)        // nbr
                     + (size_t)N_NODES * sizeof(int)              // cnt
                     + (size_t)N_NODES * sizeof(float) * 2        // deg, rsd
                     + (size_t)N_NODES * CAP * sizeof(int2)       // ej
                     + (size_t)N_NODES * HID * sizeof(float)      // H
                     + (size_t)N_NODES * FPAD * sizeof(float) * 3 // F0, FA, FB
                     + 64;                                        // lam table
  const size_t pbuf = (size_t)N_NODES * HID * sizeof(float);
  int ksplit = (ws_size >= fixed + 16 * pbuf) ? 16 : 8;

  char* w = (char*)d_ws;
  int*   nbr = (int*)w;   w += (size_t)N_NODES * CAP * sizeof(int);
  int*   cnt = (int*)w;   w += (size_t)N_NODES * sizeof(int);
  float* deg = (float*)w; w += (size_t)N_NODES * sizeof(float);
  float* rsd = (float*)w; w += (size_t)N_NODES * sizeof(float);
  int2*  ej  = (int2*)w;  w += (size_t)N_NODES * CAP * sizeof(int2);
  float* P   = (float*)w; w += (size_t)ksplit * N_NODES * HID * sizeof(float);
  float* H   = (float*)w; w += (size_t)N_NODES * HID * sizeof(float);
  float* F0  = (float*)w; w += (size_t)N_NODES * FPAD * sizeof(float);
  float* FA  = (float*)w; w += (size_t)N_NODES * FPAD * sizeof(float);
  float* FB  = (float*)w; w += (size_t)N_NODES * FPAD * sizeof(float);
  float* lamt = (float*)w;

  build_adj<<<N_NODES, 256, 0, stream>>>(A, nbr, cnt, deg, rsd, lamt, lg0, rd);
  pack_edges<<<N_NODES, 128, 0, stream>>>(nbr, cnt, rsd, ej);
  gemm1<<<dim3(N_NODES / BR, ksplit), 256, 0, stream>>>(X, w1, P, ksplit);
  reduce_h<<<(N_NODES * HID / 4) / 256, 256, 0, stream>>>(P, H, ksplit);
  mlp_out<<<(N_NODES * FPAD) / 256, 256, 0, stream>>>(H, b1, w2, b2, F0, FA);

  float* cur = FA;
  float* nxt = FB;
  for (int k = 0; k < 10; ++k) {
    int last = (k == 9);
    float* dst = last ? out : nxt;
    rung_step<<<(N_NODES * LPN) / 256, 256, 0, stream>>>(cur, F0, dst, ej, cnt,
                                                         deg, rsd, lamt, k, last);
    float* tmp = cur; cur = nxt; nxt = tmp;
  }
}